// Round 2
// baseline (289.626 us; speedup 1.0000x reference)
//
#include <hip/hip_runtime.h>
#include <hip/hip_cooperative_groups.h>

namespace cg = cooperative_groups;

// Faster-RCNN box-head postprocess, ONE cooperative dispatch.
// Round-1 showed per-dispatch overhead (~20 us/stage) dominates the
// controllable time; kernel interiors are small. So: fuse the verified
// 3-kernel pipeline into one cooperative kernel with grid.sync() between
// phases. Phase interiors are bit-identical to the round-0 code.
// Phase 1 (all 256 blocks): per-row softmax offset + max fg score key.
// Phase 2 (blocks 0..B-1): per-image row-max hist -> lb -> hot rows ->
//          collect -> entry hist -> lb2 -> compact -> bitonic sort -> decode.
// Phase 3 (all blocks): parallel feature gather.
#define NCLS 91
#define NFG 90
#define NDET 100
#define FDIM 1024
#define CAP 4096
#define NBUK 4096
#define BBOX_CLIP 4.135166556742356f
#define TPB 1024
#define NBLK 256

// Parallel suffix-scan threshold finder over a 4096-bucket LDS histogram.
// tid<256 threads own 16 buckets each; finds lb = floor of highest bucket b
// where count(keys >= b) crosses `target` from above. All threads must call.
__device__ __forceinline__ void find_threshold(const unsigned* hist,
                                               unsigned* wsum, unsigned* sh_lb,
                                               int tid, unsigned target) {
    unsigned local[16]; unsigned s = 0, run = 0;
    if (tid < 256) {
        #pragma unroll
        for (int i = 0; i < 16; i++) { local[i] = hist[tid * 16 + i]; s += local[i]; }
        run = s;
        #pragma unroll
        for (int off = 1; off < 64; off <<= 1) {     // in-wave inclusive suffix
            unsigned v = __shfl_down(run, off);
            if ((tid & 63) + off < 64) run += v;
        }
        if ((tid & 63) == 0) wsum[tid >> 6] = run;   // 4 wave totals
    }
    __syncthreads();
    if (tid < 256) {
        int w = tid >> 6;
        #pragma unroll
        for (int ww = 0; ww < 4; ww++) if (ww > w) run += wsum[ww];
        unsigned above = run - s;                    // strictly above my chunk
        #pragma unroll
        for (int i = 15; i >= 0; i--) {
            unsigned prev = above; above += local[i];
            if (above >= target && prev < target)
                *sh_lb = ((unsigned)(tid * 16 + i)) << 20;
        }
    }
    __syncthreads();
}

__global__ __launch_bounds__(TPB) void fused_all(
        const float* __restrict__ logits, const float* __restrict__ reg,
        const float* __restrict__ props, const float* __restrict__ feats,
        const int* __restrict__ pH, const int* __restrict__ pW,
        float* __restrict__ rowoff, unsigned* __restrict__ maxk,
        unsigned* __restrict__ keepRow,
        float* __restrict__ outBoxes, float* __restrict__ outFeats,
        int N, int P, int B) {
    __shared__ unsigned long long cand[CAP];    // 32 KB
    __shared__ unsigned long long cbuf[2048];   // 16 KB; also hot-row u32[4096]
    __shared__ unsigned hist[NBUK];             // 16 KB
    __shared__ unsigned wsum[4];
    __shared__ unsigned sh_lb, sh_lb2, sh_nhot, sh_ncand, sh_n2;

    cg::grid_group grid = cg::this_grid();
    const int tid = threadIdx.x;
    const int wave = tid >> 6, lane = tid & 63;

    // ---------- Phase 1: per-row softmax offset + max fg key ----------
    {
        const int nwaves = NBLK * (TPB >> 6);
        const int gw = blockIdx.x * (TPB >> 6) + wave;
        for (long long row = gw; row < N; row += nwaves) {
            const float* r = logits + row * NCLS;
            float l1 = r[lane];                              // classes 0..63
            float l2 = (lane < NCLS - 64) ? r[64 + lane] : -INFINITY;  // 64..90
            // fg max first; global max = fmax(fg max, class-0 logit)
            float mf = fmaxf((lane == 0) ? -INFINITY : l1, l2);
            #pragma unroll
            for (int o = 32; o; o >>= 1) mf = fmaxf(mf, __shfl_xor(mf, o));
            float m = fmaxf(mf, __shfl(l1, 0));              // bitwise same as full max
            float e = expf(l1 - m) + ((lane < NCLS - 64) ? expf(l2 - m) : 0.0f);
            #pragma unroll
            for (int o = 32; o; o >>= 1) e += __shfl_xor(e, o);
            float off = m + logf(e);                         // same bits all lanes
            // expf monotone => key of max fg logit == max over fg entry keys
            unsigned km = __float_as_uint(expf(mf - off));
            if (lane == 0) { rowoff[row] = off; maxk[row] = km; }
        }
    }
    grid.sync();

    // ---------- Phase 2: per-image select + decode (blocks 0..B-1) ----------
    if (blockIdx.x < (unsigned)B) {
        const int img = blockIdx.x;
        const unsigned* mk = maxk + (size_t)img * P;
        unsigned* hot = (unsigned*)cbuf;

        if (tid == 0) { sh_nhot = 0; sh_ncand = 0; sh_n2 = 0; sh_lb = 0; sh_lb2 = 0; }
        for (int b = tid; b < NBUK; b += TPB) hist[b] = 0u;
        __syncthreads();

        // --- row-max histogram (top 12 key bits) -> lb_row ---
        for (int r = tid; r < P; r += TPB) atomicAdd(&hist[mk[r] >> 20], 1u);
        __syncthreads();
        find_threshold(hist, wsum, &sh_lb, tid, NDET);
        const unsigned lb = sh_lb;          // lb <= M100 <= T
        const unsigned lbh = lb ? lb - 1 : 0;   // 1-ulp slack for maxk monotonicity

        // --- hot rows: maxk >= lb-1 (superset of rows feeding the top-100) ---
        for (int r = tid; r < P; r += TPB)
            if (mk[r] >= lbh) hot[atomicAdd(&sh_nhot, 1u)] = (unsigned)r;
        __syncthreads();
        const int nhot = (int)sh_nhot;

        // --- collect entries >= lb from hot rows (wave per row) ---
        for (int i = wave; i < nhot; i += TPB / 64) {
            int rl = (int)hot[i];
            long long row = (long long)img * P + rl;
            float off = rowoff[row];
            const float* r = logits + row * NCLS;
            float l1 = r[lane];
            float l2 = (lane < NCLS - 64) ? r[64 + lane] : -INFINITY;
            if (lane >= 1) {
                unsigned k = __float_as_uint(expf(l1 - off));
                if (k >= lb) {
                    unsigned pos = atomicAdd(&sh_ncand, 1u);
                    if (pos < CAP)
                        cand[pos] = ((unsigned long long)k << 32) |
                                    (unsigned)(0xFFFFFFFFu - (unsigned)(rl * NFG + lane - 1));
                }
            }
            if (lane < NCLS - 64) {
                unsigned k = __float_as_uint(expf(l2 - off));
                if (k >= lb) {
                    unsigned pos = atomicAdd(&sh_ncand, 1u);
                    if (pos < CAP)
                        cand[pos] = ((unsigned long long)k << 32) |
                                    (unsigned)(0xFFFFFFFFu - (unsigned)(rl * NFG + 63 + lane));
                }
            }
        }
        __syncthreads();
        unsigned cnt = sh_ncand; if (cnt > CAP) cnt = CAP;
        int n;

        if (cnt > 128) {
            // --- entry-level refinement: 12-bit hist of candidate keys -> lb_ent ---
            for (int b = tid; b < NBUK; b += TPB) hist[b] = 0u;
            __syncthreads();
            for (int i = tid; i < (int)cnt; i += TPB)
                atomicAdd(&hist[(unsigned)(cand[i] >> 52)], 1u);
            __syncthreads();
            find_threshold(hist, wsum, &sh_lb2, tid, NDET);
            unsigned lb2 = sh_lb2;          // lb2 >= lb, count(keys >= lb2) >= NDET
            // --- compact keys >= lb2 into cbuf ---
            for (int i = tid; i < (int)cnt; i += TPB) {
                unsigned long long k64 = cand[i];
                if ((unsigned)(k64 >> 32) >= lb2) {
                    unsigned pos = atomicAdd(&sh_n2, 1u);
                    if (pos < 2048) cbuf[pos] = k64;
                }
            }
            __syncthreads();
            unsigned cnt2 = sh_n2;
            if (cnt2 <= 2048) {             // expected path (ties pathologies excluded)
                cnt = cnt2;
                n = 128; while (n < (int)cnt) n <<= 1;
                for (int i = tid; i < n; i += TPB)
                    cand[i] = (i < (int)cnt) ? cbuf[i] : 0ULL;
                __syncthreads();
            } else {
                n = 128; while (n < (int)cnt) n <<= 1;
                for (int i = tid; i < n; i += TPB) if (i >= (int)cnt) cand[i] = 0ULL;
                __syncthreads();
            }
        } else {
            n = 128;
            for (int i = tid; i < n; i += TPB) if (i >= (int)cnt) cand[i] = 0ULL;
            __syncthreads();
        }

        // --- ascending bitonic sort of n keys; top-100 at n-1 .. n-100 ---
        for (int k = 2; k <= n; k <<= 1) {
            for (int j = k >> 1; j > 0; j >>= 1) {
                for (int i = tid; i < n; i += TPB) {
                    int ixj = i ^ j;
                    if (ixj > i) {
                        bool up = ((i & k) == 0);
                        unsigned long long a = cand[i], b = cand[ixj];
                        if ((a > b) == up) { cand[i] = b; cand[ixj] = a; }
                    }
                }
                __syncthreads();
            }
        }

        // --- decode + clip + normalize top-100 boxes; record feature rows ---
        if (tid < NDET) {
            unsigned long long key = cand[n - 1 - tid];
            unsigned e = 0xFFFFFFFFu - (unsigned)(key & 0xFFFFFFFFull);
            int pr = e / NFG, cm = e - pr * NFG, c = cm + 1;
            long long rw = (long long)img * P + pr;
            float x1 = props[rw * 4 + 0], y1 = props[rw * 4 + 1];
            float x2 = props[rw * 4 + 2], y2 = props[rw * 4 + 3];
            float w = x2 - x1, hgt = y2 - y1;
            float cx = x1 + 0.5f * w, cy = y1 + 0.5f * hgt;
            const float* rr = reg + rw * (4 * NCLS) + 4 * c;
            float dx = rr[0] / 10.0f, dy = rr[1] / 10.0f;
            float dw = fminf(rr[2] / 5.0f, BBOX_CLIP);
            float dh = fminf(rr[3] / 5.0f, BBOX_CLIP);
            float pcx = dx * w + cx, pcy = dy * hgt + cy;
            float pw_ = expf(dw) * w, ph_ = expf(dh) * hgt;
            float bx1 = pcx - 0.5f * pw_, by1 = pcy - 0.5f * ph_;
            float bx2 = pcx + 0.5f * pw_, by2 = pcy + 0.5f * ph_;
            float W = (float)(*pW), H = (float)(*pH);
            bx1 = fminf(fmaxf(bx1, 0.0f), W);
            bx2 = fminf(fmaxf(bx2, 0.0f), W);
            by1 = fminf(fmaxf(by1, 0.0f), H);
            by2 = fminf(fmaxf(by2, 0.0f), H);
            int o = (img * NDET + tid) * 4;
            outBoxes[o + 0] = bx1 / H;
            outBoxes[o + 1] = by1 / H;
            outBoxes[o + 2] = bx2 / H;
            outBoxes[o + 3] = by2 / H;
            keepRow[img * NDET + tid] = (unsigned)rw;
        }
    }
    grid.sync();

    // ---------- Phase 3: feature gather (4×256-thread groups per block) ----------
    {
        const int ndet = B * NDET;
        const int grp = tid >> 8, sub = tid & 255;   // 4 groups of 256
        for (int det = (int)blockIdx.x * 4 + grp; det < ndet; det += NBLK * 4) {
            long long r = keepRow[det];
            const float4* src = (const float4*)(feats + r * FDIM);
            float4* dst = (float4*)(outFeats + (long long)det * FDIM);
            dst[sub] = src[sub];   // 256 × 16B = 4 KB per detection
        }
    }
}

extern "C" void kernel_launch(void* const* d_in, const int* in_sizes, int n_in,
                              void* d_out, int out_size, void* d_ws, size_t ws_size,
                              hipStream_t stream) {
    const float* logits = (const float*)d_in[0];
    const float* reg    = (const float*)d_in[1];
    const float* props  = (const float*)d_in[2];
    const float* feats  = (const float*)d_in[3];
    const int*   pH     = (const int*)d_in[5];
    const int*   pW     = (const int*)d_in[6];

    int N = in_sizes[0] / NCLS;               // total proposals (B*P)
    int B = out_size / (NDET * (4 + FDIM));   // 8
    int P = N / B;

    // workspace: rowoff [N] f32 | maxk [N] u32 | keepRow [B*NDET] u32
    char* ws = (char*)d_ws;
    float*    rowoff  = (float*)ws;
    unsigned* maxk    = (unsigned*)(rowoff + N);
    unsigned* keepRow = (unsigned*)(maxk + N);

    float* outBoxes = (float*)d_out;
    float* outFeats = outBoxes + (size_t)B * NDET * 4;

    void* args[] = { &logits, &reg, &props, &feats, &pH, &pW,
                     &rowoff, &maxk, &keepRow, &outBoxes, &outFeats,
                     &N, &P, &B };
    hipLaunchCooperativeKernel((const void*)fused_all, dim3(NBLK), dim3(TPB),
                               args, 0, stream);
}

// Round 3
// 273.185 us; speedup vs baseline: 1.0602x; 1.0602x over previous
//
#include <hip/hip_runtime.h>

// Faster-RCNN box-head postprocess, 2 regular dispatches.
// Round-2 analysis: cooperative launch costs ~60us harness overhead (revert);
// phase-2 select was ~55-60us serial on 8 CUs. This version distributes
// phase 2 over 16 blocks/image: each block independently rebuilds the
// per-image row-max histogram from maxk (identical lb in all blocks),
// collects candidates from its slice into LDS, publishes with ONE global
// atomicAdd per block (round-1's per-entry atomic storm removed), and the
// last-finishing block per image (device-scope done counter + threadfence;
// standard last-block pattern, no co-residency assumption) runs the verified
// refine -> compact -> bitonic sort -> decode tail plus the feature gather.
// Keys are unique (low word packs ~entry index) so the full sort gives a
// deterministic, bit-identical result regardless of arrival order.
// K1: per-row softmax offset + max fg score key; block 0 zeroes counters.
// K2: distributed select + last-block finalize (sort, decode, feat gather).
#define NCLS 91
#define NFG 90
#define NDET 100
#define FDIM 1024
#define NBUK 4096
#define CAP_G 16384         // per-image global candidate capacity
#define CAP_L 4096          // LDS candidate/sort capacity
#define HOT_CAP 512
#define BBOX_CLIP 4.135166556742356f
#define K1_TPB 256
#define RPB 32              // rows per K1 block (8 per wave)
#define K2_TPB 1024
#define GPB 16              // K2 blocks per image

// ---------------- K1: softmax offset + per-row max fg key ----------------
__global__ __launch_bounds__(K1_TPB) void k1_soft(
        const float* __restrict__ logits, float* __restrict__ rowoff,
        unsigned* __restrict__ maxk, unsigned* __restrict__ counters,
        int N, int B) {
    // zero gcnt[B] + gdone[B] (contiguous); dispatch boundary orders vs K2
    if (blockIdx.x == 0 && threadIdx.x < (unsigned)(2 * B))
        counters[threadIdx.x] = 0u;
    int wave = threadIdx.x >> 6, lane = threadIdx.x & 63;
    int rowbase = blockIdx.x * RPB + wave * (RPB / 4);
    for (int it = 0; it < RPB / 4; it++) {
        long long row = rowbase + it;
        if (row >= N) return;
        const float* r = logits + row * NCLS;
        float l1 = r[lane];                              // classes 0..63
        float l2 = (lane < NCLS - 64) ? r[64 + lane] : -INFINITY;  // 64..90
        // fg max first; global max = fmax(fg max, class-0 logit)
        float mf = fmaxf((lane == 0) ? -INFINITY : l1, l2);
        #pragma unroll
        for (int o = 32; o; o >>= 1) mf = fmaxf(mf, __shfl_xor(mf, o));
        float m = fmaxf(mf, __shfl(l1, 0));              // bitwise same as full max
        float e = expf(l1 - m) + ((lane < NCLS - 64) ? expf(l2 - m) : 0.0f);
        #pragma unroll
        for (int o = 32; o; o >>= 1) e += __shfl_xor(e, o);
        float off = m + logf(e);                         // same bits all lanes
        // expf monotone => key of max fg logit == max over fg entry keys
        unsigned km = __float_as_uint(expf(mf - off));
        if (lane == 0) { rowoff[row] = off; maxk[row] = km; }
    }
}

// Parallel suffix-scan threshold finder over a 4096-bucket LDS histogram.
// tid<256 threads own 16 buckets each; finds lb = floor of highest bucket b
// where count(keys >= b) crosses `target` from above. All threads must call.
__device__ __forceinline__ void find_threshold(const unsigned* hist,
                                               unsigned* wsum, unsigned* sh_lb,
                                               int tid, unsigned target) {
    unsigned local[16]; unsigned s = 0, run = 0;
    if (tid < 256) {
        #pragma unroll
        for (int i = 0; i < 16; i++) { local[i] = hist[tid * 16 + i]; s += local[i]; }
        run = s;
        #pragma unroll
        for (int off = 1; off < 64; off <<= 1) {     // in-wave inclusive suffix
            unsigned v = __shfl_down(run, off);
            if ((tid & 63) + off < 64) run += v;
        }
        if ((tid & 63) == 0) wsum[tid >> 6] = run;   // 4 wave totals
    }
    __syncthreads();
    if (tid < 256) {
        int w = tid >> 6;
        #pragma unroll
        for (int ww = 0; ww < 4; ww++) if (ww > w) run += wsum[ww];
        unsigned above = run - s;                    // strictly above my chunk
        #pragma unroll
        for (int i = 15; i >= 0; i--) {
            unsigned prev = above; above += local[i];
            if (above >= target && prev < target)
                *sh_lb = ((unsigned)(tid * 16 + i)) << 20;
        }
    }
    __syncthreads();
}

// ---------------- K2: distributed select + last-block finalize ----------------
__global__ __launch_bounds__(K2_TPB) void k2_all(
        const float* __restrict__ logits, const float* __restrict__ reg,
        const float* __restrict__ props, const float* __restrict__ feats,
        const int* __restrict__ pH, const int* __restrict__ pW,
        const float* __restrict__ rowoff, const unsigned* __restrict__ maxk,
        unsigned long long* __restrict__ gcand, unsigned* __restrict__ gcnt,
        unsigned* __restrict__ gdone,
        float* __restrict__ outBoxes, float* __restrict__ outFeats, int P) {
    __shared__ unsigned long long cand[CAP_L];  // 32 KB (collect, then sort)
    __shared__ unsigned hist[NBUK];             // 16 KB
    __shared__ unsigned hot[HOT_CAP];           // 2 KB
    __shared__ unsigned keepL[NDET];
    __shared__ unsigned wsum[4];
    __shared__ unsigned sh_lb, sh_lb2, sh_nhot, sh_nc, sh_base, sh_done, sh_n2;

    const int img = blockIdx.x / GPB, sub = blockIdx.x % GPB;
    const int tid = threadIdx.x, wave = tid >> 6, lane = tid & 63;

    if (tid == 0) { sh_lb = 0; sh_lb2 = 0; sh_nhot = 0; sh_nc = 0; sh_n2 = 0; }
    for (int b = tid; b < NBUK; b += K2_TPB) hist[b] = 0u;
    __syncthreads();

    // --- every block rebuilds the full per-image row-max histogram (16 KB,
    //     L2/L3-resident) -> identical integer data -> identical lb ---
    const unsigned* mk = maxk + (size_t)img * P;
    for (int r = tid; r < P; r += K2_TPB) atomicAdd(&hist[mk[r] >> 20], 1u);
    __syncthreads();
    find_threshold(hist, wsum, &sh_lb, tid, NDET);
    const unsigned lb = sh_lb;          // lb <= M100 <= T
    const unsigned lbh = lb ? lb - 1 : 0;   // 1-ulp slack for maxk monotonicity

    // --- hot rows in my slice: maxk >= lb-1 (coalesced scan) ---
    const int chunk = (P + GPB - 1) / GPB;
    const int r0 = sub * chunk;
    const int r1 = (r0 + chunk < P) ? (r0 + chunk) : P;
    for (int r = r0 + tid; r < r1; r += K2_TPB)
        if (mk[r] >= lbh) {
            unsigned hp = atomicAdd(&sh_nhot, 1u);
            if (hp < HOT_CAP) hot[hp] = (unsigned)r;
        }
    __syncthreads();
    int nhot = (int)sh_nhot; if (nhot > HOT_CAP) nhot = HOT_CAP;

    // --- collect entries >= lb from hot rows (wave per row) into LDS ---
    for (int i = wave; i < nhot; i += K2_TPB / 64) {
        int rl = (int)hot[i];
        long long row = (long long)img * P + rl;
        float off = rowoff[row];
        const float* r = logits + row * NCLS;
        float l1 = r[lane];
        float l2 = (lane < NCLS - 64) ? r[64 + lane] : -INFINITY;
        if (lane >= 1) {
            unsigned k = __float_as_uint(expf(l1 - off));
            if (k >= lb) {
                unsigned pos = atomicAdd(&sh_nc, 1u);
                if (pos < CAP_L)
                    cand[pos] = ((unsigned long long)k << 32) |
                                (unsigned)(0xFFFFFFFFu - (unsigned)(rl * NFG + lane - 1));
            }
        }
        if (lane < NCLS - 64) {
            unsigned k = __float_as_uint(expf(l2 - off));
            if (k >= lb) {
                unsigned pos = atomicAdd(&sh_nc, 1u);
                if (pos < CAP_L)
                    cand[pos] = ((unsigned long long)k << 32) |
                                (unsigned)(0xFFFFFFFFu - (unsigned)(rl * NFG + 63 + lane));
            }
        }
    }
    __syncthreads();
    unsigned nc = sh_nc; if (nc > CAP_L) nc = CAP_L;

    // --- publish: ONE global atomic per block + coalesced copy ---
    if (tid == 0) sh_base = atomicAdd(&gcnt[img], nc);
    __syncthreads();
    unsigned base = sh_base;
    unsigned long long* gc = gcand + (size_t)img * CAP_G;
    for (unsigned i = tid; i < nc; i += K2_TPB)
        if (base + i < CAP_G) gc[base + i] = cand[i];
    __threadfence();                       // release my gc writes
    __syncthreads();
    if (tid == 0) sh_done = atomicAdd(&gdone[img], 1u);
    __syncthreads();
    if (sh_done != GPB - 1) return;        // not the last block for this image

    // ================= finalize (exactly one block per image) =================
    __threadfence();                       // acquire all blocks' gc writes
    __syncthreads();
    unsigned cnt = gcnt[img]; if (cnt > CAP_G) cnt = CAP_G;

    for (int b = tid; b < NBUK; b += K2_TPB) hist[b] = 0u;
    __syncthreads();
    int n;
    if (cnt > 128) {
        // --- entry-level refinement: 12-bit hist of candidate keys -> lb2 ---
        for (int i = tid; i < (int)cnt; i += K2_TPB)
            atomicAdd(&hist[(unsigned)(gc[i] >> 52)], 1u);
        __syncthreads();
        find_threshold(hist, wsum, &sh_lb2, tid, NDET);
        unsigned lb2 = sh_lb2;             // count(keys >= lb2) >= NDET
        // --- compact keys >= lb2 into LDS ---
        for (int i = tid; i < (int)cnt; i += K2_TPB) {
            unsigned long long k64 = gc[i];
            if ((unsigned)(k64 >> 32) >= lb2) {
                unsigned pos = atomicAdd(&sh_n2, 1u);
                if (pos < CAP_L) cand[pos] = k64;
            }
        }
        __syncthreads();
        unsigned c2 = sh_n2; if (c2 > CAP_L) c2 = CAP_L;
        n = 128; while (n < (int)c2) n <<= 1;
        for (int i = tid; i < n; i += K2_TPB) if (i >= (int)c2) cand[i] = 0ULL;
        __syncthreads();
    } else {
        n = 128;
        for (int i = tid; i < n; i += K2_TPB) cand[i] = (i < (int)cnt) ? gc[i] : 0ULL;
        __syncthreads();
    }

    // --- ascending bitonic sort of n keys; top-100 at n-1 .. n-100 ---
    for (int k = 2; k <= n; k <<= 1) {
        for (int j = k >> 1; j > 0; j >>= 1) {
            for (int i = tid; i < n; i += K2_TPB) {
                int ixj = i ^ j;
                if (ixj > i) {
                    bool up = ((i & k) == 0);
                    unsigned long long a = cand[i], b = cand[ixj];
                    if ((a > b) == up) { cand[i] = b; cand[ixj] = a; }
                }
            }
            __syncthreads();
        }
    }

    // --- decode + clip + normalize top-100 boxes ---
    if (tid < NDET) {
        unsigned long long key = cand[n - 1 - tid];
        unsigned e = 0xFFFFFFFFu - (unsigned)(key & 0xFFFFFFFFull);
        int pr = e / NFG, cm = e - pr * NFG, c = cm + 1;
        long long rw = (long long)img * P + pr;
        float x1 = props[rw * 4 + 0], y1 = props[rw * 4 + 1];
        float x2 = props[rw * 4 + 2], y2 = props[rw * 4 + 3];
        float w = x2 - x1, hgt = y2 - y1;
        float cx = x1 + 0.5f * w, cy = y1 + 0.5f * hgt;
        const float* rr = reg + rw * (4 * NCLS) + 4 * c;
        float dx = rr[0] / 10.0f, dy = rr[1] / 10.0f;
        float dw = fminf(rr[2] / 5.0f, BBOX_CLIP);
        float dh = fminf(rr[3] / 5.0f, BBOX_CLIP);
        float pcx = dx * w + cx, pcy = dy * hgt + cy;
        float pw_ = expf(dw) * w, ph_ = expf(dh) * hgt;
        float bx1 = pcx - 0.5f * pw_, by1 = pcy - 0.5f * ph_;
        float bx2 = pcx + 0.5f * pw_, by2 = pcy + 0.5f * ph_;
        float W = (float)(*pW), H = (float)(*pH);
        bx1 = fminf(fmaxf(bx1, 0.0f), W);
        bx2 = fminf(fmaxf(bx2, 0.0f), W);
        by1 = fminf(fmaxf(by1, 0.0f), H);
        by2 = fminf(fmaxf(by2, 0.0f), H);
        int o = (img * NDET + tid) * 4;
        outBoxes[o + 0] = bx1 / H;
        outBoxes[o + 1] = by1 / H;
        outBoxes[o + 2] = bx2 / H;
        outBoxes[o + 3] = by2 / H;
        keepL[tid] = (unsigned)rw;
    }
    __syncthreads();

    // --- feature gather for this image (4 x 256-thread groups) ---
    {
        const int grp = tid >> 8, subl = tid & 255;
        for (int d = grp; d < NDET; d += 4) {
            long long r = keepL[d];
            const float4* src = (const float4*)(feats + r * FDIM);
            float4* dst = (float4*)(outFeats + ((long long)img * NDET + d) * FDIM);
            dst[subl] = src[subl];          // 256 x 16B = 4 KB per detection
        }
    }
}

extern "C" void kernel_launch(void* const* d_in, const int* in_sizes, int n_in,
                              void* d_out, int out_size, void* d_ws, size_t ws_size,
                              hipStream_t stream) {
    const float* logits = (const float*)d_in[0];
    const float* reg    = (const float*)d_in[1];
    const float* props  = (const float*)d_in[2];
    const float* feats  = (const float*)d_in[3];
    const int*   pH     = (const int*)d_in[5];
    const int*   pW     = (const int*)d_in[6];

    int N = in_sizes[0] / NCLS;               // total proposals (B*P)
    int B = out_size / (NDET * (4 + FDIM));   // 8
    int P = N / B;

    // workspace: gcand [B*CAP_G] u64 | rowoff [N] f32 | maxk [N] u32 |
    //            gcnt [B] u32 | gdone [B] u32   (gcnt/gdone contiguous)
    char* ws = (char*)d_ws;
    unsigned long long* gcand = (unsigned long long*)ws;
    float*    rowoff = (float*)(gcand + (size_t)B * CAP_G);
    unsigned* maxk   = (unsigned*)(rowoff + N);
    unsigned* gcnt   = (unsigned*)(maxk + N);
    unsigned* gdone  = gcnt + B;

    float* outBoxes = (float*)d_out;
    float* outFeats = outBoxes + (size_t)B * NDET * 4;

    k1_soft<<<(N + RPB - 1) / RPB, K1_TPB, 0, stream>>>(logits, rowoff, maxk,
                                                        gcnt, N, B);
    k2_all<<<B * GPB, K2_TPB, 0, stream>>>(logits, reg, props, feats, pH, pW,
                                           rowoff, maxk, gcand, gcnt, gdone,
                                           outBoxes, outFeats, P);
}

// Round 4
// 231.648 us; speedup vs baseline: 1.2503x; 1.1793x over previous
//
#include <hip/hip_runtime.h>

// Faster-RCNN box-head postprocess, 3 regular dispatches (round-0 skeleton:
// every device-scope-sync alternative measured 45-65us slower on gfx950).
// Bound used: M100 = 100th-largest per-row max key <= T (100th-largest entry),
// so a threshold from the P row-max keys lower-bounds T; rows with
// maxk >= lb contain the whole top-100. Candidates >= lb are refined with an
// entry-level 12-bit histogram, then ranked by counting (replaces the bitonic
// sort: rank = #{keys > me} over unique keys == sort position; bit-identical).
// K1: per-row softmax offset + max fg score key (1 expf for the key, monotone).
// K2: row-max hist (ballot-aggregated) -> lb -> hot rows -> collect ->
//     entry hist -> lb2 -> compact -> rank-by-count -> box decode.
// K3: parallel feature gather.
#define NCLS 91
#define NFG 90
#define NDET 100
#define FDIM 1024
#define CAP 4096
#define NBUK 4096
#define BBOX_CLIP 4.135166556742356f
#define K1_TPB 256
#define RPB 32             // rows per K1 block (8 per wave)
#define K2_TPB 1024

// ---------------- K1: softmax offset + per-row max fg key ----------------
__global__ __launch_bounds__(K1_TPB) void k1_soft(
        const float* __restrict__ logits, float* __restrict__ rowoff,
        unsigned* __restrict__ maxk, int N) {
    int wave = threadIdx.x >> 6, lane = threadIdx.x & 63;
    int rowbase = blockIdx.x * RPB + wave * (RPB / 4);
    for (int it = 0; it < RPB / 4; it++) {
        long long row = rowbase + it;
        if (row >= N) return;
        const float* r = logits + row * NCLS;
        float l1 = r[lane];                              // classes 0..63
        float l2 = (lane < NCLS - 64) ? r[64 + lane] : -INFINITY;  // 64..90
        // fg max first; global max = fmax(fg max, class-0 logit)
        float mf = fmaxf((lane == 0) ? -INFINITY : l1, l2);
        #pragma unroll
        for (int o = 32; o; o >>= 1) mf = fmaxf(mf, __shfl_xor(mf, o));
        float m = fmaxf(mf, __shfl(l1, 0));              // bitwise same as full max
        float e = expf(l1 - m) + ((lane < NCLS - 64) ? expf(l2 - m) : 0.0f);
        #pragma unroll
        for (int o = 32; o; o >>= 1) e += __shfl_xor(e, o);
        float off = m + logf(e);                         // same bits all lanes
        // expf monotone => key of max fg logit == max over fg entry keys
        unsigned km = __float_as_uint(expf(mf - off));
        if (lane == 0) { rowoff[row] = off; maxk[row] = km; }
    }
}

// Parallel suffix-scan threshold finder over a 4096-bucket LDS histogram.
// tid<256 threads own 16 buckets each; finds lb = floor of highest bucket b
// where count(keys >= b) crosses `target` from above. All threads must call.
__device__ __forceinline__ void find_threshold(const unsigned* hist,
                                               unsigned* wsum, unsigned* sh_lb,
                                               int tid, unsigned target) {
    unsigned local[16]; unsigned s = 0, run = 0;
    if (tid < 256) {
        #pragma unroll
        for (int i = 0; i < 16; i++) { local[i] = hist[tid * 16 + i]; s += local[i]; }
        run = s;
        #pragma unroll
        for (int off = 1; off < 64; off <<= 1) {     // in-wave inclusive suffix
            unsigned v = __shfl_down(run, off);
            if ((tid & 63) + off < 64) run += v;
        }
        if ((tid & 63) == 0) wsum[tid >> 6] = run;   // 4 wave totals
    }
    __syncthreads();
    if (tid < 256) {
        int w = tid >> 6;
        #pragma unroll
        for (int ww = 0; ww < 4; ww++) if (ww > w) run += wsum[ww];
        unsigned above = run - s;                    // strictly above my chunk
        #pragma unroll
        for (int i = 15; i >= 0; i--) {
            unsigned prev = above; above += local[i];
            if (above >= target && prev < target)
                *sh_lb = ((unsigned)(tid * 16 + i)) << 20;
        }
    }
    __syncthreads();
}

// ---------------- K2: per-image select + box decode ----------------
__global__ __launch_bounds__(K2_TPB) void k2_select(
        const float* __restrict__ logits, const float* __restrict__ reg,
        const float* __restrict__ props,
        const int* __restrict__ pH, const int* __restrict__ pW,
        const float* __restrict__ rowoff, const unsigned* __restrict__ maxk,
        float* __restrict__ outBoxes, unsigned* __restrict__ keepRow, int P) {
    __shared__ unsigned long long cand[CAP];    // 32 KB
    __shared__ unsigned long long cbuf[2048];   // 16 KB; also hot-row u32[4096]
    __shared__ unsigned hist[NBUK];             // 16 KB
    __shared__ unsigned long long win[NDET];    // 800 B ranked winners
    __shared__ unsigned wsum[4];
    __shared__ unsigned sh_lb, sh_lb2, sh_nhot, sh_ncand, sh_n2;

    const int img = blockIdx.x;
    const int tid = threadIdx.x;
    const unsigned* mk = maxk + (size_t)img * P;
    unsigned* hot = (unsigned*)cbuf;

    if (tid == 0) { sh_nhot = 0; sh_ncand = 0; sh_n2 = 0; sh_lb = 0; sh_lb2 = 0; }
    for (int b = tid; b < NBUK; b += K2_TPB) hist[b] = 0u;
    __syncthreads();

    // --- row-max histogram (top 12 key bits) -> lb_row ---
    // maxk values cluster into few buckets (float bits of exp() in (0,1)):
    // wave-leader aggregation issues one atomic per distinct bucket per wave
    // instead of 64 same-address lane-serialized atomics.
    {
        const int lane = tid & 63;
        for (int r = tid; r < P + (K2_TPB - 1); r += K2_TPB) {
            unsigned b = (r < P) ? (mk[r] >> 20) : 0xFFFFFFFFu;
            bool done = (r >= P);
            while (true) {
                unsigned long long m = __ballot(!done);
                if (!m) break;
                int leader = __ffsll((long long)m) - 1;
                unsigned lb_ = __shfl(b, leader);
                bool mine = (!done && b == lb_);
                unsigned long long grp = __ballot(mine);
                if (lane == leader) atomicAdd(&hist[lb_], (unsigned)__popcll(grp));
                if (mine) done = true;
            }
        }
    }
    __syncthreads();
    find_threshold(hist, wsum, &sh_lb, tid, NDET);
    const unsigned lb = sh_lb;          // lb <= M100 <= T
    const unsigned lbh = lb ? lb - 1 : 0;   // 1-ulp slack for maxk monotonicity

    // --- hot rows: maxk >= lb-1 (superset of rows feeding the top-100) ---
    for (int r = tid; r < P; r += K2_TPB)
        if (mk[r] >= lbh) hot[atomicAdd(&sh_nhot, 1u)] = (unsigned)r;
    __syncthreads();
    const int nhot = (int)sh_nhot;

    // --- collect entries >= lb from hot rows (wave per row) ---
    const int wave = tid >> 6, lane = tid & 63;
    for (int i = wave; i < nhot; i += K2_TPB / 64) {
        int rl = (int)hot[i];
        long long row = (long long)img * P + rl;
        float off = rowoff[row];
        const float* r = logits + row * NCLS;
        float l1 = r[lane];
        float l2 = (lane < NCLS - 64) ? r[64 + lane] : -INFINITY;
        if (lane >= 1) {
            unsigned k = __float_as_uint(expf(l1 - off));
            if (k >= lb) {
                unsigned pos = atomicAdd(&sh_ncand, 1u);
                if (pos < CAP)
                    cand[pos] = ((unsigned long long)k << 32) |
                                (unsigned)(0xFFFFFFFFu - (unsigned)(rl * NFG + lane - 1));
            }
        }
        if (lane < NCLS - 64) {
            unsigned k = __float_as_uint(expf(l2 - off));
            if (k >= lb) {
                unsigned pos = atomicAdd(&sh_ncand, 1u);
                if (pos < CAP)
                    cand[pos] = ((unsigned long long)k << 32) |
                                (unsigned)(0xFFFFFFFFu - (unsigned)(rl * NFG + 63 + lane));
            }
        }
    }
    __syncthreads();
    unsigned cnt = sh_ncand; if (cnt > CAP) cnt = CAP;

    const unsigned long long* pool = cand;
    unsigned pcnt = cnt;                // >= NDET guaranteed (each hot row's max >= lb)

    if (cnt > 128) {
        // --- entry-level refinement: 12-bit hist of candidate keys -> lb_ent ---
        for (int b = tid; b < NBUK; b += K2_TPB) hist[b] = 0u;
        __syncthreads();
        for (int i = tid; i < (int)cnt; i += K2_TPB)
            atomicAdd(&hist[(unsigned)(cand[i] >> 52)], 1u);
        __syncthreads();
        find_threshold(hist, wsum, &sh_lb2, tid, NDET);
        unsigned lb2 = sh_lb2;          // lb2 >= lb, count(keys >= lb2) >= NDET
        // --- compact keys >= lb2 into cbuf ---
        for (int i = tid; i < (int)cnt; i += K2_TPB) {
            unsigned long long k64 = cand[i];
            if ((unsigned)(k64 >> 32) >= lb2) {
                unsigned pos = atomicAdd(&sh_n2, 1u);
                if (pos < 2048) cbuf[pos] = k64;
            }
        }
        __syncthreads();
        unsigned cnt2 = sh_n2;
        if (cnt2 <= 2048) { pool = cbuf; pcnt = cnt2; }  // expected path
        // else: pathological tie storm; rank over the full cand set (correct,
        // just slower) — pool/pcnt already set.
    }

    // --- rank-by-count: rank = #{keys > me}; unique keys => rank == position
    //     in the descending sort (bit-identical to the old bitonic output).
    //     Wave per candidate; lanes stride the pool (conflict-free reads). ---
    for (unsigned i = wave; i < pcnt; i += K2_TPB / 64) {
        unsigned long long me = pool[i];
        unsigned ng = 0;
        for (unsigned j = lane; j < pcnt; j += 64)
            ng += (pool[j] > me) ? 1u : 0u;
        #pragma unroll
        for (int o = 32; o; o >>= 1) ng += __shfl_xor(ng, o);
        if (lane == 0 && ng < NDET) win[ng] = me;
    }
    __syncthreads();

    // --- decode + clip + normalize top-100 boxes; record feature rows ---
    if (tid < NDET) {
        unsigned long long key = win[tid];
        unsigned e = 0xFFFFFFFFu - (unsigned)(key & 0xFFFFFFFFull);
        int pr = e / NFG, cm = e - pr * NFG, c = cm + 1;
        long long rw = (long long)img * P + pr;
        float x1 = props[rw * 4 + 0], y1 = props[rw * 4 + 1];
        float x2 = props[rw * 4 + 2], y2 = props[rw * 4 + 3];
        float w = x2 - x1, hgt = y2 - y1;
        float cx = x1 + 0.5f * w, cy = y1 + 0.5f * hgt;
        const float* rr = reg + rw * (4 * NCLS) + 4 * c;
        float dx = rr[0] / 10.0f, dy = rr[1] / 10.0f;
        float dw = fminf(rr[2] / 5.0f, BBOX_CLIP);
        float dh = fminf(rr[3] / 5.0f, BBOX_CLIP);
        float pcx = dx * w + cx, pcy = dy * hgt + cy;
        float pw_ = expf(dw) * w, ph_ = expf(dh) * hgt;
        float bx1 = pcx - 0.5f * pw_, by1 = pcy - 0.5f * ph_;
        float bx2 = pcx + 0.5f * pw_, by2 = pcy + 0.5f * ph_;
        float W = (float)(*pW), H = (float)(*pH);
        bx1 = fminf(fmaxf(bx1, 0.0f), W);
        bx2 = fminf(fmaxf(bx2, 0.0f), W);
        by1 = fminf(fmaxf(by1, 0.0f), H);
        by2 = fminf(fmaxf(by2, 0.0f), H);
        int o = (img * NDET + tid) * 4;
        outBoxes[o + 0] = bx1 / H;
        outBoxes[o + 1] = by1 / H;
        outBoxes[o + 2] = bx2 / H;
        outBoxes[o + 3] = by2 / H;
        keepRow[img * NDET + tid] = (unsigned)rw;
    }
}

// ---------------- K3: feature gather (1 det per block, float4) ----------------
__global__ __launch_bounds__(256) void k3_feats(
        const float* __restrict__ feats, const unsigned* __restrict__ keepRow,
        float* __restrict__ outF) {
    int det = blockIdx.x;
    long long r = keepRow[det];
    const float4* src = (const float4*)(feats + r * FDIM);
    float4* dst = (float4*)(outF + (long long)det * FDIM);
    dst[threadIdx.x] = src[threadIdx.x];
}

extern "C" void kernel_launch(void* const* d_in, const int* in_sizes, int n_in,
                              void* d_out, int out_size, void* d_ws, size_t ws_size,
                              hipStream_t stream) {
    const float* logits = (const float*)d_in[0];
    const float* reg    = (const float*)d_in[1];
    const float* props  = (const float*)d_in[2];
    const float* feats  = (const float*)d_in[3];
    const int*   pH     = (const int*)d_in[5];
    const int*   pW     = (const int*)d_in[6];

    int N = in_sizes[0] / NCLS;               // total proposals (B*P)
    int B = out_size / (NDET * (4 + FDIM));   // 8
    int P = N / B;

    // workspace: rowoff [N] f32 | maxk [N] u32 | keepRow [B*NDET] u32
    char* ws = (char*)d_ws;
    float*    rowoff  = (float*)ws;
    unsigned* maxk    = (unsigned*)(rowoff + N);
    unsigned* keepRow = (unsigned*)(maxk + N);

    float* outBoxes = (float*)d_out;
    float* outFeats = outBoxes + (size_t)B * NDET * 4;

    k1_soft<<<(N + RPB - 1) / RPB, K1_TPB, 0, stream>>>(logits, rowoff, maxk, N);
    k2_select<<<B, K2_TPB, 0, stream>>>(logits, reg, props, pH, pW,
                                        rowoff, maxk, outBoxes, keepRow, P);
    k3_feats<<<B * NDET, 256, 0, stream>>>(feats, keepRow, outFeats);
}